// Round 1
// baseline (40408.063 us; speedup 1.0000x reference)
//
#include <hip/hip_runtime.h>

#define HID 64
#define NF 8
#define IND 14

__device__ __forceinline__ float sigm(float x) {
  return 1.0f / (1.0f + __expf(-x));
}
__device__ __forceinline__ float tanh_fast(float x) {
  float ax = fabsf(x);
  float e = __expf(-2.0f * ax);         // no overflow: e in (0,1]
  float r = (1.0f - e) / (1.0f + e);
  return x < 0.0f ? -r : r;
}

// Single persistent block, 256 threads (4 waves, 1 wave/SIMD -> 512 VGPR budget).
// Thread g owns gate-row g of W_hh0, W_hh1, W_ih1 (+ W_ih0 row, W_hid segment)
// in registers. Phases per step (4 barriers):
//   P1: gates0 dot + layer1 recurrent dot (accB, reg) + hid[t-1] partials
//   P2: layer0 activation -> h0s | hid[t-1] finalize | x[t+1] -> LDS
//   P3: gates1 = accB + W_ih1 @ h0_new | x-projection for step t+1 (off path)
//   P4: layer1 activation -> h1s | out[t-1] = round(W_out @ hid[t-1]) -> global
__global__ __launch_bounds__(256, 1) void decoder_seq(
    const float* __restrict__ h0in, const float* __restrict__ c0in,
    const float* __restrict__ diffp, const float* __restrict__ target,
    const float* __restrict__ Wih0, const float* __restrict__ Whh0,
    const float* __restrict__ bih0, const float* __restrict__ bhh0,
    const float* __restrict__ Wih1, const float* __restrict__ Whh1,
    const float* __restrict__ bih1, const float* __restrict__ bhh1,
    const float* __restrict__ Whid, const float* __restrict__ bhidp,
    const float* __restrict__ Woutp, const float* __restrict__ boutp,
    float* __restrict__ outp, const int T)
{
  const int tid = threadIdx.x;

  __shared__ alignas(16) float h0s[HID];
  __shared__ alignas(16) float h1s[HID];
  __shared__ alignas(16) float g0s[4 * HID];
  __shared__ alignas(16) float g1s[4 * HID];
  __shared__ alignas(16) float hidpart[256];
  __shared__ alignas(16) float hidb[32];
  __shared__ alignas(16) float xb[16];

  // ---- per-thread weight registers (fully unrolled accesses only) ----
  float wx[IND];     // W_ih0 row g
  float wh0[HID];    // W_hh0 row g
  float whh1r[HID];  // W_hh1 row g
  float wih1r[HID];  // W_ih1 row g
  float whidr[8];    // W_hid[j][sg*8 .. sg*8+8), j = g>>3, sg = g&7
  float woutr[32];   // W_out row (threads 64..71 only)
  float bias0, bias1;
  float bhid_r = 0.0f, bout_r = 0.0f, diff_r = 0.0f;

  {
    const int g = tid;
    #pragma unroll
    for (int k = 0; k < IND; ++k) wx[k] = Wih0[g * IND + k];
    const float4* p0 = (const float4*)&Whh0[g * HID];
    const float4* p1 = (const float4*)&Whh1[g * HID];
    const float4* p2 = (const float4*)&Wih1[g * HID];
    #pragma unroll
    for (int kk = 0; kk < 16; ++kk) {
      float4 a = p0[kk];
      wh0[4*kk+0] = a.x; wh0[4*kk+1] = a.y; wh0[4*kk+2] = a.z; wh0[4*kk+3] = a.w;
      float4 b = p1[kk];
      whh1r[4*kk+0] = b.x; whh1r[4*kk+1] = b.y; whh1r[4*kk+2] = b.z; whh1r[4*kk+3] = b.w;
      float4 c = p2[kk];
      wih1r[4*kk+0] = c.x; wih1r[4*kk+1] = c.y; wih1r[4*kk+2] = c.z; wih1r[4*kk+3] = c.w;
    }
    bias0 = bih0[g] + bhh0[g];
    bias1 = bih1[g] + bhh1[g];
    const int j = g >> 3, sg = g & 7;
    const float4* ph = (const float4*)&Whid[j * HID + sg * 8];
    float4 ha = ph[0], hb = ph[1];
    whidr[0] = ha.x; whidr[1] = ha.y; whidr[2] = ha.z; whidr[3] = ha.w;
    whidr[4] = hb.x; whidr[5] = hb.y; whidr[6] = hb.z; whidr[7] = hb.w;
  }
  if (tid >= 64 && tid < 96) bhid_r = bhidp[tid - 64];
  if (tid >= 64 && tid < 72) {
    const float4* pw = (const float4*)&Woutp[(tid - 64) * 32];
    #pragma unroll
    for (int kk = 0; kk < 8; ++kk) {
      float4 w = pw[kk];
      woutr[4*kk+0] = w.x; woutr[4*kk+1] = w.y; woutr[4*kk+2] = w.z; woutr[4*kk+3] = w.w;
    }
    bout_r = boutp[tid - 64];
  }
  if (tid >= 104 && tid < 110) diff_r = diffp[tid - 104];

  float c0r = 0.0f, c1r = 0.0f;
  if (tid < 64) {
    h0s[tid] = h0in[tid];
    h1s[tid] = h0in[64 + tid];
    c0r = c0in[tid];
    c1r = c0in[64 + tid];
  }
  float xc  = 0.0f;   // x-projection contribution for step t (t=0: x = zeros)
  float tpf = 0.0f;   // target prefetch register
  __syncthreads();

  for (int t = 0; t < T; ++t) {
    float accB;
    // ---------------- P1 ----------------
    if (tid >= 96 && tid < 104) tpf = target[t * NF + (tid - 96)];
    {
      const float4* h04 = (const float4*)h0s;
      const float4* h14 = (const float4*)h1s;
      float a0 = bias0 + xc, a1 = 0.f, a2 = 0.f, a3 = 0.f;
      float b0 = bias1,      b1 = 0.f, b2 = 0.f, b3 = 0.f;
      #pragma unroll
      for (int kk = 0; kk < 16; ++kk) {
        float4 hv = h04[kk];
        a0 += wh0[4*kk+0] * hv.x; a1 += wh0[4*kk+1] * hv.y;
        a2 += wh0[4*kk+2] * hv.z; a3 += wh0[4*kk+3] * hv.w;
        float4 hw = h14[kk];
        b0 += whh1r[4*kk+0] * hw.x; b1 += whh1r[4*kk+1] * hw.y;
        b2 += whh1r[4*kk+2] * hw.z; b3 += whh1r[4*kk+3] * hw.w;
      }
      g0s[tid] = (a0 + a1) + (a2 + a3);
      accB     = (b0 + b1) + (b2 + b3);
      const int sg = tid & 7;
      float4 p = h14[sg * 2], q = h14[sg * 2 + 1];   // h1[t-1] -> hid[t-1] partial
      hidpart[tid] = ((whidr[0]*p.x + whidr[1]*p.y) + (whidr[2]*p.z + whidr[3]*p.w))
                   + ((whidr[4]*q.x + whidr[5]*q.y) + (whidr[6]*q.z + whidr[7]*q.w));
    }
    __syncthreads();
    // ---------------- P2 ----------------
    if (tid < 64) {
      float gi = g0s[tid], gf = g0s[64+tid], gg = g0s[128+tid], go = g0s[192+tid];
      c0r = sigm(gf) * c0r + sigm(gi) * tanh_fast(gg);
      h0s[tid] = sigm(go) * tanh_fast(c0r);
    } else if (tid < 96) {
      const int j = tid - 64;
      const float4* hp = (const float4*)&hidpart[j * 8];
      float4 p = hp[0], q = hp[1];
      hidb[j] = bhid_r + (((p.x+p.y) + (p.z+p.w)) + ((q.x+q.y) + (q.z+q.w)));
    } else if (tid < 104) {
      xb[tid - 96] = tpf;              // x[t+1][0:8] = target[t]
    } else if (tid < 110) {
      xb[8 + tid - 104] = diff_r;      // x[t+1][8:14] = difficulty
    }
    __syncthreads();
    // ---------------- P3 ----------------
    {
      const float4* h04 = (const float4*)h0s;
      float a0 = accB, a1 = 0.f, a2 = 0.f, a3 = 0.f;
      #pragma unroll
      for (int kk = 0; kk < 16; ++kk) {
        float4 hv = h04[kk];
        a0 += wih1r[4*kk+0] * hv.x; a1 += wih1r[4*kk+1] * hv.y;
        a2 += wih1r[4*kk+2] * hv.z; a3 += wih1r[4*kk+3] * hv.w;
      }
      g1s[tid] = (a0 + a1) + (a2 + a3);
      // x-projection for step t+1 (off the critical path)
      float x0 = 0.f, x1 = 0.f;
      #pragma unroll
      for (int k = 0; k < IND; k += 2) {
        x0 += wx[k] * xb[k];
        x1 += wx[k+1] * xb[k+1];
      }
      xc = x0 + x1;
    }
    __syncthreads();
    // ---------------- P4 ----------------
    if (tid < 64) {
      float gi = g1s[tid], gf = g1s[64+tid], gg = g1s[128+tid], go = g1s[192+tid];
      c1r = sigm(gf) * c1r + sigm(gi) * tanh_fast(gg);
      h1s[tid] = sigm(go) * tanh_fast(c1r);
    } else if (tid < 72 && t > 0) {
      const float4* hb4 = (const float4*)hidb;
      float s0 = bout_r, s1 = 0.f, s2 = 0.f, s3 = 0.f;
      #pragma unroll
      for (int kk = 0; kk < 8; ++kk) {
        float4 h = hb4[kk];
        s0 += woutr[4*kk+0] * h.x; s1 += woutr[4*kk+1] * h.y;
        s2 += woutr[4*kk+2] * h.z; s3 += woutr[4*kk+3] * h.w;
      }
      outp[(t - 1) * NF + (tid - 64)] = rintf((s0 + s1) + (s2 + s3));
    }
    __syncthreads();
  }

  // ---------------- epilogue: out[T-1] + final states ----------------
  {
    const float4* h14 = (const float4*)h1s;
    const int sg = tid & 7;
    float4 p = h14[sg * 2], q = h14[sg * 2 + 1];
    hidpart[tid] = ((whidr[0]*p.x + whidr[1]*p.y) + (whidr[2]*p.z + whidr[3]*p.w))
                 + ((whidr[4]*q.x + whidr[5]*q.y) + (whidr[6]*q.z + whidr[7]*q.w));
  }
  if (tid < 64) {
    const int base = T * NF;
    outp[base + tid]       = h0s[tid];   // h_final layer 0
    outp[base + 64 + tid]  = h1s[tid];   // h_final layer 1
    outp[base + 128 + tid] = c0r;        // c_final layer 0
    outp[base + 192 + tid] = c1r;        // c_final layer 1
  }
  __syncthreads();
  if (tid >= 64 && tid < 96) {
    const int j = tid - 64;
    const float4* hp = (const float4*)&hidpart[j * 8];
    float4 p = hp[0], q = hp[1];
    hidb[j] = bhid_r + (((p.x+p.y) + (p.z+p.w)) + ((q.x+q.y) + (q.z+q.w)));
  }
  __syncthreads();
  if (tid >= 64 && tid < 72) {
    const float4* hb4 = (const float4*)hidb;
    float s0 = bout_r, s1 = 0.f, s2 = 0.f, s3 = 0.f;
    #pragma unroll
    for (int kk = 0; kk < 8; ++kk) {
      float4 h = hb4[kk];
      s0 += woutr[4*kk+0] * h.x; s1 += woutr[4*kk+1] * h.y;
      s2 += woutr[4*kk+2] * h.z; s3 += woutr[4*kk+3] * h.w;
    }
    outp[(T - 1) * NF + (tid - 64)] = rintf((s0 + s1) + (s2 + s3));
  }
}

extern "C" void kernel_launch(void* const* d_in, const int* in_sizes, int n_in,
                              void* d_out, int out_size, void* d_ws, size_t ws_size,
                              hipStream_t stream) {
  // setup_inputs order:
  // 0 encoder_out (unused), 1 h0, 2 c0, 3 difficulty, 4 target,
  // 5 W_ih0, 6 W_hh0, 7 b_ih0, 8 b_hh0, 9 W_ih1, 10 W_hh1, 11 b_ih1, 12 b_hh1,
  // 13 W_hid, 14 b_hid, 15 W_out, 16 b_out
  const float* h0in   = (const float*)d_in[1];
  const float* c0in   = (const float*)d_in[2];
  const float* diffp  = (const float*)d_in[3];
  const float* target = (const float*)d_in[4];
  const float* Wih0   = (const float*)d_in[5];
  const float* Whh0   = (const float*)d_in[6];
  const float* bih0   = (const float*)d_in[7];
  const float* bhh0   = (const float*)d_in[8];
  const float* Wih1   = (const float*)d_in[9];
  const float* Whh1   = (const float*)d_in[10];
  const float* bih1   = (const float*)d_in[11];
  const float* bhh1   = (const float*)d_in[12];
  const float* Whid   = (const float*)d_in[13];
  const float* bhidp  = (const float*)d_in[14];
  const float* Woutp  = (const float*)d_in[15];
  const float* boutp  = (const float*)d_in[16];
  float* outp = (float*)d_out;
  const int T = in_sizes[4] / NF;

  decoder_seq<<<dim3(1), dim3(256), 0, stream>>>(
      h0in, c0in, diffp, target,
      Wih0, Whh0, bih0, bhh0,
      Wih1, Whh1, bih1, bhh1,
      Whid, bhidp, Woutp, boutp,
      outp, T);
}

// Round 2
// 32196.860 us; speedup vs baseline: 1.2550x; 1.2550x over previous
//
#include <hip/hip_runtime.h>

#define HID 64
#define NF 8
#define IND 14

typedef float f2 __attribute__((ext_vector_type(2)));
typedef float f4 __attribute__((ext_vector_type(4)));

__device__ __forceinline__ float tanh_fast(float x) {
  float ax = fabsf(x);
  float e = __expf(-2.0f * ax);              // in (0,1]
  float r = __fdividef(1.0f - e, 1.0f + e);
  return x < 0.0f ? -r : r;
}

// compute sigma(x) and tanh(x) (both), select by lane role (k==2 -> tanh)
__device__ __forceinline__ float act_gate(float x, bool is_tanh_lane) {
  float e = __expf(-x);
  float s = __fdividef(1.0f, 1.0f + e);
  float t = tanh_fast(x);
  return is_tanh_lane ? t : s;
}

template <int CTRL>
__device__ __forceinline__ float qp(float x) {
  return __int_as_float(
      __builtin_amdgcn_update_dpp(0, __float_as_int(x), CTRL, 0xF, 0xF, true));
}

// One persistent block, 256 threads (4 waves, 1/SIMD).
// Lane mapping: wave w = tid>>6, l = tid&63, quad q = l>>2, gate k = l&3.
// Unit u = 16*w + q. Gate-row r = 64*k + u  (torch order i,f,g,o = k 0..3).
// All 4 gates of unit u live in one quad -> activation via 3 quad_perm DPPs,
// no barrier. 2 barriers/step total:
//   Phase A: gates0 dot (Whh0.h0 + xc) | accB = Whh1.h1 | hidpart(t-1) |
//            outpart(t-2) | act0 -> h0s[wb]   [+ flush/prefetch 1/32 steps]
//   Phase B: gates1 = accB + Wih1.h0 | act1 -> h1s | xproj(t+1) |
//            hidb(t-1) | outfinal(t-2) -> obuf
__global__ __launch_bounds__(256, 1) void decoder_seq(
    const float* __restrict__ h0in, const float* __restrict__ c0in,
    const float* __restrict__ diffp, const float* __restrict__ target,
    const float* __restrict__ Wih0, const float* __restrict__ Whh0,
    const float* __restrict__ bih0, const float* __restrict__ bhh0,
    const float* __restrict__ Wih1, const float* __restrict__ Whh1,
    const float* __restrict__ bih1, const float* __restrict__ bhh1,
    const float* __restrict__ Whid, const float* __restrict__ bhidp,
    const float* __restrict__ Woutp, const float* __restrict__ boutp,
    float* __restrict__ outp, const int T)
{
  const int tid = threadIdx.x;
  const int w = tid >> 6;
  const int l = tid & 63;
  const int q = l >> 2;
  const int k = l & 3;
  const int u = 16 * w + q;        // hidden unit
  const int r = 64 * k + u;        // gate row
  const bool isg = (k == 2);
  const bool isk0 = (k == 0);

  __shared__ alignas(16) float h0s[2][HID];
  __shared__ alignas(16) float h1s[HID];
  __shared__ alignas(16) float hidpart[256];
  __shared__ alignas(16) float hidb[32];
  __shared__ alignas(16) float outpart[32];
  __shared__ alignas(16) float obuf[32 * NF];      // 32-step output ring
  __shared__ alignas(16) float tbuf[2 * 32 * NF];  // target double buffer

  // ---- per-thread weight registers ----
  f2 wh0v[32], whh1v[32], wih1v[32], wxv[4], whidv[4], woutv[4];
  float bias0r, bias1r, xc_diff;
  float bhid_r = 0.0f, bout_r = 0.0f;

  {
    const f4* p0 = (const f4*)&Whh0[r * HID];
    const f4* p1 = (const f4*)&Whh1[r * HID];
    const f4* p2 = (const f4*)&Wih1[r * HID];
    #pragma unroll
    for (int kk = 0; kk < 16; ++kk) {
      f4 a = p0[kk]; wh0v[2*kk] = a.lo;  wh0v[2*kk+1] = a.hi;
      f4 b = p1[kk]; whh1v[2*kk] = b.lo; whh1v[2*kk+1] = b.hi;
      f4 c = p2[kk]; wih1v[2*kk] = c.lo; wih1v[2*kk+1] = c.hi;
    }
    float wx[IND];
    #pragma unroll
    for (int m = 0; m < IND; ++m) wx[m] = Wih0[r * IND + m];
    wxv[0] = (f2){wx[0], wx[1]}; wxv[1] = (f2){wx[2], wx[3]};
    wxv[2] = (f2){wx[4], wx[5]}; wxv[3] = (f2){wx[6], wx[7]};
    xc_diff = 0.0f;
    #pragma unroll
    for (int m = 0; m < 6; ++m) xc_diff += wx[8 + m] * diffp[m];
    bias0r = bih0[r] + bhh0[r];
    bias1r = bih1[r] + bhh1[r];
    // hidpart weights: j = tid>>3 (0..31), seg = tid&7
    const int j = tid >> 3, seg = tid & 7;
    const f4* ph = (const f4*)&Whid[j * HID + seg * 8];
    f4 ha = ph[0], hb = ph[1];
    whidv[0] = ha.lo; whidv[1] = ha.hi; whidv[2] = hb.lo; whidv[3] = hb.hi;
  }
  if (tid >= 64 && tid < 96) bhid_r = bhidp[tid - 64];
  if (tid >= 96 && tid < 104) bout_r = boutp[tid - 96];
  if (tid >= 192 && tid < 224) {
    const int idx = tid - 192, f = idx >> 2, sg = idx & 3;
    const f4* pw = (const f4*)&Woutp[f * 32 + sg * 8];
    f4 wa = pw[0], wb = pw[1];
    woutv[0] = wa.lo; woutv[1] = wa.hi; woutv[2] = wb.lo; woutv[3] = wb.hi;
  }

  float c0r = 0.0f, c1r = 0.0f;
  if (isk0) { c0r = c0in[u]; c1r = c0in[64 + u]; }
  if (tid < 64) { h0s[0][tid] = h0in[tid]; h1s[tid] = h0in[64 + tid]; }
  // preload target chunks 0,1
  if (tid >= 128 && tid < 192) {
    const int lane = tid - 128;
    #pragma unroll
    for (int c = 0; c < 2; ++c) {
      if (c * 32 < T) {
        f4 tv = *(const f4*)&target[c * 256 + lane * 4];
        *(f4*)&tbuf[c * 256 + lane * 4] = tv;
      }
    }
  }
  float xc = 0.0f;  // x[0] = zeros
  __syncthreads();

  for (int t = 0; t < T; ++t) {
    const int rb = t & 1, wb = rb ^ 1;
    // ================= PHASE A =================
    if ((t & 31) == 2 && t >= 34 && tid >= 128 && tid < 192) {
      const int lane = tid - 128;
      // flush outs [t-34 .. t-3]
      f4 val = *(const f4*)&obuf[lane * 4];
      *(f4*)&outp[(t - 34) * NF + lane * 4] = val;
      // prefetch target chunk
      const int cl = ((t - 2) >> 5) + 1;
      if (cl * 32 < T) {
        f4 tv = *(const f4*)&target[cl * 256 + lane * 4];
        *(f4*)&tbuf[(cl & 1) * 256 + lane * 4] = tv;
      }
    }
    f2 accB0, accB1;
    {
      const f4* h0v = (const f4*)h0s[rb];
      const f4* h1v = (const f4*)h1s;
      f2 aA = {bias0r + xc, 0.0f}, aA2 = {0.0f, 0.0f};
      f2 aB = {bias1r, 0.0f},      aB2 = {0.0f, 0.0f};
      #pragma unroll
      for (int kk = 0; kk < 16; ++kk) {
        f4 hv = h0v[kk];
        aA  += wh0v[2*kk]    * hv.lo;
        aA2 += wh0v[2*kk+1]  * hv.hi;
        f4 hw = h1v[kk];
        aB  += whh1v[2*kk]   * hw.lo;
        aB2 += whh1v[2*kk+1] * hw.hi;
      }
      accB0 = aB; accB1 = aB2;
      float ga = (aA.x + aA2.x) + (aA.y + aA2.y);
      // hidpart(t-1): reads h1s = h1[t-1]
      {
        const f4* hseg = (const f4*)&h1s[(tid & 7) * 8];
        f4 p = hseg[0], qv = hseg[1];
        f2 hp = whidv[0] * p.lo;
        hp += whidv[1] * p.hi;
        hp += whidv[2] * qv.lo;
        hp += whidv[3] * qv.hi;
        hidpart[tid] = hp.x + hp.y;
      }
      // outpart(t-2): Wout[f][seg8] . hidb[seg8]
      if (tid >= 192 && tid < 224) {
        const int idx = tid - 192, sg = idx & 3;
        const f4* hb4 = (const f4*)&hidb[sg * 8];
        f4 p = hb4[0], qv = hb4[1];
        f2 op = woutv[0] * p.lo;
        op += woutv[1] * p.hi;
        op += woutv[2] * qv.lo;
        op += woutv[3] * qv.hi;
        outpart[idx] = op.x + op.y;
      }
      // act0 (all lanes), quad exchange, k0 combines
      float a = act_gate(ga, isg);
      float A1 = qp<0xB1>(a);   // lane0 <- sigma(f)
      float A2 = qp<0x4E>(a);   // lane0 <- tanh(g)
      float A3 = qp<0x1B>(a);   // lane0 <- sigma(o)
      if (isk0) {
        c0r = A1 * c0r + a * A2;
        h0s[wb][u] = A3 * tanh_fast(c0r);
      }
    }
    __syncthreads();
    // ================= PHASE B =================
    {
      const f4* h0v = (const f4*)h0s[wb];
      #pragma unroll
      for (int kk = 0; kk < 16; ++kk) {
        f4 hv = h0v[kk];
        accB0 += wih1v[2*kk]   * hv.lo;
        accB1 += wih1v[2*kk+1] * hv.hi;
      }
      float gb = (accB0.x + accB1.x) + (accB0.y + accB1.y);
      float a = act_gate(gb, isg);
      float A1 = qp<0xB1>(a);
      float A2 = qp<0x4E>(a);
      float A3 = qp<0x1B>(a);
      if (isk0) {
        c1r = A1 * c1r + a * A2;
        h1s[u] = A3 * tanh_fast(c1r);
      }
      // x-projection for step t+1 from target[t]
      {
        const f4* trow = (const f4*)&tbuf[((t >> 5) & 1) * 256 + (t & 31) * 8];
        f4 r0 = trow[0], r1 = trow[1];
        f2 xa = wxv[0] * r0.lo;
        xa += wxv[1] * r0.hi;
        xa += wxv[2] * r1.lo;
        xa += wxv[3] * r1.hi;
        xc = xc_diff + xa.x + xa.y;
      }
      // hidb(t-1)
      if (tid >= 64 && tid < 96) {
        const int j = tid - 64;
        const f4* hp = (const f4*)&hidpart[j * 8];
        f4 p = hp[0], qv = hp[1];
        hidb[j] = bhid_r + (((p.x + p.y) + (p.z + p.w)) +
                            ((qv.x + qv.y) + (qv.z + qv.w)));
      }
      // outfinal(t-2) -> obuf
      if (t >= 2 && tid >= 96 && tid < 104) {
        const int f = tid - 96;
        f4 v = *(const f4*)&outpart[4 * f];
        float s = (v.x + v.y) + (v.z + v.w) + bout_r;
        obuf[((t - 2) & 31) * NF + f] = rintf(s);
      }
    }
    __syncthreads();
  }

  // ================= EPILOGUE =================
  // E1: hidpart(T-1), outpart(T-2)
  {
    const f4* hseg = (const f4*)&h1s[(tid & 7) * 8];
    f4 p = hseg[0], qv = hseg[1];
    f2 hp = whidv[0] * p.lo;
    hp += whidv[1] * p.hi;
    hp += whidv[2] * qv.lo;
    hp += whidv[3] * qv.hi;
    hidpart[tid] = hp.x + hp.y;
  }
  if (tid >= 192 && tid < 224) {
    const int idx = tid - 192, sg = idx & 3;
    const f4* hb4 = (const f4*)&hidb[sg * 8];
    f4 p = hb4[0], qv = hb4[1];
    f2 op = woutv[0] * p.lo;
    op += woutv[1] * p.hi;
    op += woutv[2] * qv.lo;
    op += woutv[3] * qv.hi;
    outpart[idx] = op.x + op.y;
  }
  __syncthreads();
  // E2: hidb(T-1), outfinal(T-2)
  if (tid >= 64 && tid < 96) {
    const int j = tid - 64;
    const f4* hp = (const f4*)&hidpart[j * 8];
    f4 p = hp[0], qv = hp[1];
    hidb[j] = bhid_r + (((p.x + p.y) + (p.z + p.w)) +
                        ((qv.x + qv.y) + (qv.z + qv.w)));
  }
  if (tid >= 96 && tid < 104) {
    const int f = tid - 96;
    f4 v = *(const f4*)&outpart[4 * f];
    float s = (v.x + v.y) + (v.z + v.w) + bout_r;
    obuf[((T - 2) & 31) * NF + f] = rintf(s);
  }
  __syncthreads();
  // E3: outpart(T-1)
  if (tid >= 192 && tid < 224) {
    const int idx = tid - 192, sg = idx & 3;
    const f4* hb4 = (const f4*)&hidb[sg * 8];
    f4 p = hb4[0], qv = hb4[1];
    f2 op = woutv[0] * p.lo;
    op += woutv[1] * p.hi;
    op += woutv[2] * qv.lo;
    op += woutv[3] * qv.hi;
    outpart[idx] = op.x + op.y;
  }
  __syncthreads();
  // E4: outfinal(T-1) + final states
  if (tid >= 96 && tid < 104) {
    const int f = tid - 96;
    f4 v = *(const f4*)&outpart[4 * f];
    float s = (v.x + v.y) + (v.z + v.w) + bout_r;
    obuf[((T - 1) & 31) * NF + f] = rintf(s);
  }
  {
    const int base = T * NF;
    const int fb = ((T - 1) & 1) ^ 1;
    if (tid < 64) {
      outp[base + tid]      = h0s[fb][tid];
      outp[base + 64 + tid] = h1s[tid];
    }
    if (isk0) {
      outp[base + 128 + u] = c0r;
      outp[base + 192 + u] = c1r;
    }
  }
  __syncthreads();
  // E5: tail flush (last 32 outs; T assumed multiple of 32, T>=64)
  if (tid >= 128 && tid < 192) {
    const int lane = tid - 128;
    const int tail_start = ((T - 34) / 32) * 32 + 32;
    f4 val = *(const f4*)&obuf[lane * 4];
    *(f4*)&outp[tail_start * NF + lane * 4] = val;
  }
}

extern "C" void kernel_launch(void* const* d_in, const int* in_sizes, int n_in,
                              void* d_out, int out_size, void* d_ws, size_t ws_size,
                              hipStream_t stream) {
  const float* h0in   = (const float*)d_in[1];
  const float* c0in   = (const float*)d_in[2];
  const float* diffp  = (const float*)d_in[3];
  const float* target = (const float*)d_in[4];
  const float* Wih0   = (const float*)d_in[5];
  const float* Whh0   = (const float*)d_in[6];
  const float* bih0   = (const float*)d_in[7];
  const float* bhh0   = (const float*)d_in[8];
  const float* Wih1   = (const float*)d_in[9];
  const float* Whh1   = (const float*)d_in[10];
  const float* bih1   = (const float*)d_in[11];
  const float* bhh1   = (const float*)d_in[12];
  const float* Whid   = (const float*)d_in[13];
  const float* bhidp  = (const float*)d_in[14];
  const float* Woutp  = (const float*)d_in[15];
  const float* boutp  = (const float*)d_in[16];
  float* outp = (float*)d_out;
  const int T = in_sizes[4] / NF;

  decoder_seq<<<dim3(1), dim3(256), 0, stream>>>(
      h0in, c0in, diffp, target,
      Wih0, Whh0, bih0, bhh0,
      Wih1, Whh1, bih1, bhh1,
      Whid, bhidp, Woutp, boutp,
      outp, T);
}